// Round 1
// baseline (2137.743 us; speedup 1.0000x reference)
//
#include <hip/hip_runtime.h>

#define N_NODES 100000
#define N_EDGES 600000
#define IN_DIM 128
#define EDGE_DIM 32
#define HIDDEN 128

// ---------------------------------------------------------------------------
// deg[n] = sum over edges of (dst==n)
__global__ void deg_kernel(const int* __restrict__ dst, float* __restrict__ deg) {
    int e = blockIdx.x * blockDim.x + threadIdx.x;
    if (e < N_EDGES) atomicAdd(&deg[dst[e]], 1.0f);
}

// ---------------------------------------------------------------------------
// For each edge e: msg = x[src[e]] + edge_attr[e] @ We + be ; agg[dst[e]] += msg
// block = 256 threads = 2 edges x 128 features
__global__ void edge_scatter_kernel(const float* __restrict__ xin,
                                    const int* __restrict__ src,
                                    const int* __restrict__ dst,
                                    const float* __restrict__ ea,
                                    const float* __restrict__ We,
                                    const float* __restrict__ be,
                                    float* __restrict__ agg) {
    __shared__ float s_ea[2][EDGE_DIM];
    int t = threadIdx.x;
    int f = t & 127;
    int g = t >> 7;                       // local edge 0/1
    int e = blockIdx.x * 2 + g;

    if (t < 2 * EDGE_DIM) {
        int le = t >> 5, k = t & 31;
        int ee = blockIdx.x * 2 + le;
        s_ea[le][k] = (ee < N_EDGES) ? ea[ee * EDGE_DIM + k] : 0.0f;
    }
    __syncthreads();

    if (e >= N_EDGES) return;
    int s = src[e];
    int d = dst[e];

    float proj = be[f];
#pragma unroll
    for (int k = 0; k < EDGE_DIM; ++k)
        proj += s_ea[g][k] * We[k * HIDDEN + f];

    float msg = xin[s * HIDDEN + f] + proj;
    atomicAdd(&agg[d * HIDDEN + f], msg);
}

// ---------------------------------------------------------------------------
// out[n] = relu( (agg[n]/max(deg,1)) @ Wl + bl + x[n] @ Wr + br )
// block = 256 threads, 8 nodes per block, each thread: 1 feature x 4 nodes
__global__ void node_update_kernel(const float* __restrict__ xin,
                                   const float* __restrict__ agg,
                                   const float* __restrict__ deg,
                                   const float* __restrict__ Wl,
                                   const float* __restrict__ bl,
                                   const float* __restrict__ Wr,
                                   const float* __restrict__ br,
                                   float* __restrict__ out) {
    __shared__ float s_mean[8][HIDDEN];
    __shared__ float s_x[8][HIDDEN];
    int t = threadIdx.x;
    int f = t & 127;
    int g = t >> 7;                        // node-group 0/1
    int n0 = blockIdx.x * 8;

    for (int i = t; i < 8 * HIDDEN; i += 256) {
        int ln = i >> 7;                   // local node
        int k = i & 127;
        int n = n0 + ln;
        float a = 0.0f, xv = 0.0f;
        if (n < N_NODES) {
            float dg = deg[n];
            dg = dg > 1.0f ? dg : 1.0f;
            a = agg[n * HIDDEN + k] / dg;
            xv = xin[n * HIDDEN + k];
        }
        s_mean[ln][k] = a;
        s_x[ln][k] = xv;
    }
    __syncthreads();

    float b = bl[f] + br[f];
    float acc0 = b, acc1 = b, acc2 = b, acc3 = b;
    int nb = g * 4;
#pragma unroll 4
    for (int k = 0; k < HIDDEN; ++k) {
        float wl = Wl[k * HIDDEN + f];
        float wr = Wr[k * HIDDEN + f];
        acc0 += s_mean[nb + 0][k] * wl + s_x[nb + 0][k] * wr;
        acc1 += s_mean[nb + 1][k] * wl + s_x[nb + 1][k] * wr;
        acc2 += s_mean[nb + 2][k] * wl + s_x[nb + 2][k] * wr;
        acc3 += s_mean[nb + 3][k] * wl + s_x[nb + 3][k] * wr;
    }
    float accs[4] = {acc0, acc1, acc2, acc3};
#pragma unroll
    for (int j = 0; j < 4; ++j) {
        int n = n0 + nb + j;
        if (n < N_NODES) {
            float v = accs[j];
            out[n * HIDDEN + f] = v > 0.0f ? v : 0.0f;
        }
    }
}

// ---------------------------------------------------------------------------
// he = [h[src], h[dst]] (256); z = relu(he@Wp1 + bp1) (128); out = z@Wp2 + bp2 (2)
// block = 256 threads, 16 edges per block, each thread: 1 feature x 8 edges
__global__ void edge_mlp_kernel(const float* __restrict__ h,
                                const int* __restrict__ src,
                                const int* __restrict__ dst,
                                const float* __restrict__ Wp1,
                                const float* __restrict__ bp1,
                                const float* __restrict__ Wp2,
                                const float* __restrict__ bp2,
                                float* __restrict__ out) {
    __shared__ float s_he[16][2 * HIDDEN];
    __shared__ float s_z[16][HIDDEN];
    int t = threadIdx.x;
    int f = t & 127;
    int g = t >> 7;                        // edge-group 0/1
    int e0 = blockIdx.x * 16;

    // stage he rows: 16 edges x 256 features
    for (int i = t; i < 16 * 256; i += 256) {
        int le = i >> 8;
        int k = i & 255;
        int e = e0 + le;
        float v = 0.0f;
        if (e < N_EDGES) {
            int node = (k < HIDDEN) ? src[e] : dst[e];
            v = h[node * HIDDEN + (k & 127)];
        }
        s_he[le][k] = v;
    }
    __syncthreads();

    float b = bp1[f];
    float acc[8];
#pragma unroll
    for (int j = 0; j < 8; ++j) acc[j] = b;
    int eb = g * 8;
#pragma unroll 4
    for (int k = 0; k < 2 * HIDDEN; ++k) {
        float w = Wp1[k * HIDDEN + f];
#pragma unroll
        for (int j = 0; j < 8; ++j)
            acc[j] += s_he[eb + j][k] * w;
    }
#pragma unroll
    for (int j = 0; j < 8; ++j)
        s_z[eb + j][f] = acc[j] > 0.0f ? acc[j] : 0.0f;
    __syncthreads();

    // final 128->2 projection: 16 edges x 2 classes = 32 dot products
    if (t < 32) {
        int le = t >> 1;
        int c = t & 1;
        int e = e0 + le;
        if (e < N_EDGES) {
            float s = bp2[c];
#pragma unroll 4
            for (int k = 0; k < HIDDEN; ++k)
                s += s_z[le][k] * Wp2[k * 2 + c];
            out[e * 2 + c] = s;
        }
    }
}

// ---------------------------------------------------------------------------
extern "C" void kernel_launch(void* const* d_in, const int* in_sizes, int n_in,
                              void* d_out, int out_size, void* d_ws, size_t ws_size,
                              hipStream_t stream) {
    const float* x   = (const float*)d_in[0];
    const int*   ei  = (const int*)d_in[1];        // [2, E]
    const float* ea  = (const float*)d_in[2];
    const float* We1 = (const float*)d_in[3];
    const float* be1 = (const float*)d_in[4];
    const float* Wl1 = (const float*)d_in[5];
    const float* bl1 = (const float*)d_in[6];
    const float* Wr1 = (const float*)d_in[7];
    const float* br1 = (const float*)d_in[8];
    const float* We2 = (const float*)d_in[9];
    const float* be2 = (const float*)d_in[10];
    const float* Wl2 = (const float*)d_in[11];
    const float* bl2 = (const float*)d_in[12];
    const float* Wr2 = (const float*)d_in[13];
    const float* br2 = (const float*)d_in[14];
    const float* Wp1 = (const float*)d_in[15];
    const float* bp1 = (const float*)d_in[16];
    const float* Wp2 = (const float*)d_in[17];
    const float* bp2 = (const float*)d_in[18];
    float* out = (float*)d_out;

    const int* src = ei;
    const int* dst = ei + N_EDGES;

    // workspace layout
    char* ws = (char*)d_ws;
    const size_t DEG_BYTES = 409600;                   // 100000*4 padded
    const size_t MAT_BYTES = (size_t)N_NODES * HIDDEN * 4;  // 51.2 MB
    float* deg = (float*)ws;
    float* agg = (float*)(ws + DEG_BYTES);
    float* h1  = (float*)(ws + DEG_BYTES + MAT_BYTES);
    float* h2  = (float*)(ws + DEG_BYTES + 2 * MAT_BYTES);

    // zero deg + agg (contiguous)
    hipMemsetAsync(ws, 0, DEG_BYTES + MAT_BYTES, stream);

    deg_kernel<<<(N_EDGES + 255) / 256, 256, 0, stream>>>(dst, deg);

    // ---- layer 1 ----
    edge_scatter_kernel<<<(N_EDGES + 1) / 2, 256, 0, stream>>>(
        x, src, dst, ea, We1, be1, agg);
    node_update_kernel<<<(N_NODES + 7) / 8, 256, 0, stream>>>(
        x, agg, deg, Wl1, bl1, Wr1, br1, h1);

    // ---- layer 2 ----
    hipMemsetAsync(agg, 0, MAT_BYTES, stream);
    edge_scatter_kernel<<<(N_EDGES + 1) / 2, 256, 0, stream>>>(
        h1, src, dst, ea, We2, be2, agg);
    node_update_kernel<<<(N_NODES + 7) / 8, 256, 0, stream>>>(
        h1, agg, deg, Wl2, bl2, Wr2, br2, h2);

    // ---- edge predictor ----
    edge_mlp_kernel<<<(N_EDGES + 15) / 16, 256, 0, stream>>>(
        h2, src, dst, Wp1, bp1, Wp2, bp2, out);
}

// Round 2
// 1500.184 us; speedup vs baseline: 1.4250x; 1.4250x over previous
//
#include <hip/hip_runtime.h>

#define N_NODES 100000
#define N_EDGES 600000
#define IN_DIM 128
#define EDGE_DIM 32
#define HIDDEN 128

typedef __attribute__((ext_vector_type(8))) short bf16x8;
typedef __attribute__((ext_vector_type(4))) float f32x4;

__device__ inline unsigned short f2bf(float f) {
    unsigned int u = __float_as_uint(f);
    unsigned int r = (u + 0x7FFF + ((u >> 16) & 1)) >> 16;  // RNE
    return (unsigned short)r;
}

// ---------------------------------------------------------------------------
// deg[n] = sum over edges of (dst==n)
__global__ void deg_kernel(const int* __restrict__ dst, float* __restrict__ deg) {
    int e = blockIdx.x * blockDim.x + threadIdx.x;
    if (e < N_EDGES) atomicAdd(&deg[dst[e]], 1.0f);
}

// ---------------------------------------------------------------------------
// For each edge e: msg = x[src[e]] + edge_attr[e] @ We + be ; agg[dst[e]] += msg
__global__ void edge_scatter_kernel(const float* __restrict__ xin,
                                    const int* __restrict__ src,
                                    const int* __restrict__ dst,
                                    const float* __restrict__ ea,
                                    const float* __restrict__ We,
                                    const float* __restrict__ be,
                                    float* __restrict__ agg) {
    __shared__ float s_ea[2][EDGE_DIM];
    int t = threadIdx.x;
    int f = t & 127;
    int g = t >> 7;
    int e = blockIdx.x * 2 + g;

    if (t < 2 * EDGE_DIM) {
        int le = t >> 5, k = t & 31;
        int ee = blockIdx.x * 2 + le;
        s_ea[le][k] = (ee < N_EDGES) ? ea[ee * EDGE_DIM + k] : 0.0f;
    }
    __syncthreads();

    if (e >= N_EDGES) return;
    int s = src[e];
    int d = dst[e];

    float proj = be[f];
#pragma unroll
    for (int k = 0; k < EDGE_DIM; ++k)
        proj += s_ea[g][k] * We[k * HIDDEN + f];

    float msg = xin[s * HIDDEN + f] + proj;
    atomicAdd(&agg[d * HIDDEN + f], msg);
}

// ---------------------------------------------------------------------------
// out[n] = relu( (agg[n]/max(deg,1)) @ Wl + bl + x[n] @ Wr + br )
__global__ void node_update_kernel(const float* __restrict__ xin,
                                   const float* __restrict__ agg,
                                   const float* __restrict__ deg,
                                   const float* __restrict__ Wl,
                                   const float* __restrict__ bl,
                                   const float* __restrict__ Wr,
                                   const float* __restrict__ br,
                                   float* __restrict__ out) {
    __shared__ float s_mean[8][HIDDEN];
    __shared__ float s_x[8][HIDDEN];
    int t = threadIdx.x;
    int f = t & 127;
    int g = t >> 7;
    int n0 = blockIdx.x * 8;

    for (int i = t; i < 8 * HIDDEN; i += 256) {
        int ln = i >> 7;
        int k = i & 127;
        int n = n0 + ln;
        float a = 0.0f, xv = 0.0f;
        if (n < N_NODES) {
            float dg = deg[n];
            dg = dg > 1.0f ? dg : 1.0f;
            a = agg[n * HIDDEN + k] / dg;
            xv = xin[n * HIDDEN + k];
        }
        s_mean[ln][k] = a;
        s_x[ln][k] = xv;
    }
    __syncthreads();

    float b = bl[f] + br[f];
    float acc0 = b, acc1 = b, acc2 = b, acc3 = b;
    int nb = g * 4;
#pragma unroll 4
    for (int k = 0; k < HIDDEN; ++k) {
        float wl = Wl[k * HIDDEN + f];
        float wr = Wr[k * HIDDEN + f];
        acc0 += s_mean[nb + 0][k] * wl + s_x[nb + 0][k] * wr;
        acc1 += s_mean[nb + 1][k] * wl + s_x[nb + 1][k] * wr;
        acc2 += s_mean[nb + 2][k] * wl + s_x[nb + 2][k] * wr;
        acc3 += s_mean[nb + 3][k] * wl + s_x[nb + 3][k] * wr;
    }
    float accs[4] = {acc0, acc1, acc2, acc3};
#pragma unroll
    for (int j = 0; j < 4; ++j) {
        int n = n0 + nb + j;
        if (n < N_NODES) {
            float v = accs[j];
            out[n * HIDDEN + f] = v > 0.0f ? v : 0.0f;
        }
    }
}

// ---------------------------------------------------------------------------
// Pre-swizzle Wp1 (fp32 [256][128]) into bf16 MFMA B-fragment order:
// flat short index = ((nt*8 + ks)*64 + lane)*8 + j
//   maps to Wp1[k = ks*32 + (lane>>4)*8 + j][n = nt*16 + (lane&15)]
__global__ void wp1_swizzle_kernel(const float* __restrict__ Wp1,
                                   unsigned short* __restrict__ Wp1s) {
    int idx = blockIdx.x * blockDim.x + threadIdx.x;  // 32768 total
    int j = idx & 7;
    int lane = (idx >> 3) & 63;
    int ks = (idx >> 9) & 7;
    int nt = (idx >> 12) & 7;
    int k = ks * 32 + ((lane >> 4) & 3) * 8 + j;
    int n = nt * 16 + (lane & 15);
    Wp1s[idx] = f2bf(Wp1[k * HIDDEN + n]);
}

// ---------------------------------------------------------------------------
// he = [h[src], h[dst]] (256); z = relu(he@Wp1 + bp1); out = z@Wp2 + bp2
// block = 256 threads = 4 waves; 64 edges/block (16/wave); MFMA 16x16x32 bf16.
// GEMM1 on matrix cores; GEMM2 (128->2) in-register via shfl_xor reduction.
#define HE_PITCH 264  // 256 + 8 bf16 pad: ds_read_b128 rows land 2-way (free)
__global__ __launch_bounds__(256) void edge_mlp_mfma_kernel(
        const float* __restrict__ h,
        const int* __restrict__ src,
        const int* __restrict__ dst,
        const unsigned short* __restrict__ Wp1s,
        const float* __restrict__ bp1,
        const float* __restrict__ Wp2,
        const float* __restrict__ bp2,
        float* __restrict__ out) {
    __shared__ unsigned short s_he[64 * HE_PITCH];  // 33792 B

    int t = threadIdx.x;
    int e0 = blockIdx.x * 64;  // N_EDGES = 64 * 9375 exactly, no tail

    // ---- stage He rows as bf16: 128 half-rows x 128 floats ----
    int lane32 = t & 31;
    int hr0 = t >> 5;
    for (int hr = hr0; hr < 128; hr += 8) {
        int e = e0 + (hr >> 1);
        int node = (hr & 1) ? dst[e] : src[e];
        float4 v = *(const float4*)&h[node * HIDDEN + lane32 * 4];
        ushort4 w;
        w.x = f2bf(v.x); w.y = f2bf(v.y); w.z = f2bf(v.z); w.w = f2bf(v.w);
        *(ushort4*)&s_he[(hr >> 1) * HE_PITCH + (hr & 1) * 128 + lane32 * 4] = w;
    }
    __syncthreads();

    // ---- GEMM1: per wave, 16 edges x 128 cols = 8 n-tiles, K=256 = 8 ksteps ----
    int wave = t >> 6;
    int lane = t & 63;
    int col = lane & 15;   // n within tile (A-read: m within tile)
    int kgrp = lane >> 4;  // 0..3

    f32x4 acc[8];
#pragma unroll
    for (int nt = 0; nt < 8; ++nt) acc[nt] = (f32x4){0.f, 0.f, 0.f, 0.f};

    const bf16x8* __restrict__ Wb = (const bf16x8*)Wp1s;
    const unsigned abase = (wave * 16 + col) * HE_PITCH + kgrp * 8;

#pragma unroll
    for (int ks = 0; ks < 8; ++ks) {
        bf16x8 afrag = *(const bf16x8*)&s_he[abase + ks * 32];
#pragma unroll
        for (int nt = 0; nt < 8; ++nt) {
            bf16x8 bfrag = Wb[(nt * 8 + ks) * 64 + lane];
            acc[nt] = __builtin_amdgcn_mfma_f32_16x16x32_bf16(afrag, bfrag, acc[nt], 0, 0, 0);
        }
    }

    // ---- bias + relu (C layout: n = nt*16+col, m = kgrp*4+reg) ----
    float z[8][4];
#pragma unroll
    for (int nt = 0; nt < 8; ++nt) {
        float b = bp1[nt * 16 + col];
#pragma unroll
        for (int r = 0; r < 4; ++r) {
            float v = acc[nt][r] + b;
            z[nt][r] = v > 0.f ? v : 0.f;
        }
    }

    // ---- GEMM2: out[m][c] = bp2[c] + sum_n z[m][n]*Wp2[n*2+c] ----
    float w2c0[8], w2c1[8];
#pragma unroll
    for (int nt = 0; nt < 8; ++nt) {
        int n = nt * 16 + col;
        w2c0[nt] = Wp2[n * 2 + 0];
        w2c1[nt] = Wp2[n * 2 + 1];
    }
    float p0[4], p1[4];
#pragma unroll
    for (int r = 0; r < 4; ++r) {
        float a0 = 0.f, a1 = 0.f;
#pragma unroll
        for (int nt = 0; nt < 8; ++nt) {
            a0 += z[nt][r] * w2c0[nt];
            a1 += z[nt][r] * w2c1[nt];
        }
        p0[r] = a0; p1[r] = a1;
    }
#pragma unroll
    for (int m = 8; m >= 1; m >>= 1) {
#pragma unroll
        for (int r = 0; r < 4; ++r) {
            p0[r] += __shfl_xor(p0[r], m);
            p1[r] += __shfl_xor(p1[r], m);
        }
    }
    if (col < 2) {
        float bias = bp2[col];
#pragma unroll
        for (int r = 0; r < 4; ++r) {
            int e = e0 + wave * 16 + kgrp * 4 + r;
            out[e * 2 + col] = (col == 0 ? p0[r] : p1[r]) + bias;
        }
    }
}

// ---------------------------------------------------------------------------
extern "C" void kernel_launch(void* const* d_in, const int* in_sizes, int n_in,
                              void* d_out, int out_size, void* d_ws, size_t ws_size,
                              hipStream_t stream) {
    const float* x   = (const float*)d_in[0];
    const int*   ei  = (const int*)d_in[1];
    const float* ea  = (const float*)d_in[2];
    const float* We1 = (const float*)d_in[3];
    const float* be1 = (const float*)d_in[4];
    const float* Wl1 = (const float*)d_in[5];
    const float* bl1 = (const float*)d_in[6];
    const float* Wr1 = (const float*)d_in[7];
    const float* br1 = (const float*)d_in[8];
    const float* We2 = (const float*)d_in[9];
    const float* be2 = (const float*)d_in[10];
    const float* Wl2 = (const float*)d_in[11];
    const float* bl2 = (const float*)d_in[12];
    const float* Wr2 = (const float*)d_in[13];
    const float* br2 = (const float*)d_in[14];
    const float* Wp1 = (const float*)d_in[15];
    const float* bp1 = (const float*)d_in[16];
    const float* Wp2 = (const float*)d_in[17];
    const float* bp2 = (const float*)d_in[18];
    float* out = (float*)d_out;

    const int* src = ei;
    const int* dst = ei + N_EDGES;

    char* ws = (char*)d_ws;
    const size_t DEG_BYTES = 409600;
    const size_t MAT_BYTES = (size_t)N_NODES * HIDDEN * 4;  // 51.2 MB
    float* deg = (float*)ws;
    float* agg = (float*)(ws + DEG_BYTES);
    float* h1  = (float*)(ws + DEG_BYTES + MAT_BYTES);
    float* h2  = (float*)(ws + DEG_BYTES + 2 * MAT_BYTES);
    // Wp1 bf16 swizzled fragments: reuse agg (dead after node_update layer 2)
    unsigned short* Wp1s = (unsigned short*)agg;

    hipMemsetAsync(ws, 0, DEG_BYTES + MAT_BYTES, stream);

    deg_kernel<<<(N_EDGES + 255) / 256, 256, 0, stream>>>(dst, deg);

    // ---- layer 1 ----
    edge_scatter_kernel<<<(N_EDGES + 1) / 2, 256, 0, stream>>>(
        x, src, dst, ea, We1, be1, agg);
    node_update_kernel<<<(N_NODES + 7) / 8, 256, 0, stream>>>(
        x, agg, deg, Wl1, bl1, Wr1, br1, h1);

    // ---- layer 2 ----
    hipMemsetAsync(agg, 0, MAT_BYTES, stream);
    edge_scatter_kernel<<<(N_EDGES + 1) / 2, 256, 0, stream>>>(
        h1, src, dst, ea, We2, be2, agg);
    node_update_kernel<<<(N_NODES + 7) / 8, 256, 0, stream>>>(
        h1, agg, deg, Wl2, bl2, Wr2, br2, h2);

    // ---- edge predictor (MFMA) ----
    wp1_swizzle_kernel<<<32768 / 256, 256, 0, stream>>>(Wp1, Wp1s);
    edge_mlp_mfma_kernel<<<N_EDGES / 64, 256, 0, stream>>>(
        h2, src, dst, Wp1s, bp1, Wp2, bp2, out);
}

// Round 3
// 1327.633 us; speedup vs baseline: 1.6102x; 1.1300x over previous
//
#include <hip/hip_runtime.h>

#define N_NODES 100000
#define N_EDGES 600000
#define IN_DIM 128
#define EDGE_DIM 32
#define HIDDEN 128
#define NBLK 391  // ceil(N_NODES/256)

typedef __attribute__((ext_vector_type(8))) short bf16x8;
typedef __attribute__((ext_vector_type(4))) float f32x4;

__device__ inline unsigned short f2bf(float f) {
    unsigned int u = __float_as_uint(f);
    unsigned int r = (u + 0x7FFF + ((u >> 16) & 1)) >> 16;  // RNE
    return (unsigned short)r;
}

// ===========================================================================
// CSR build
// ===========================================================================
__global__ void hist_kernel(const int* __restrict__ dst, int* __restrict__ cnt) {
    int e = blockIdx.x * blockDim.x + threadIdx.x;
    if (e < N_EDGES) atomicAdd(&cnt[dst[e]], 1);
}

// per-block (256) inclusive scan + block sums
__global__ void scan1_kernel(const int* __restrict__ cnt,
                             int* __restrict__ scanout, int* __restrict__ bsum) {
    __shared__ int s[256];
    int tid = threadIdx.x;
    int i = blockIdx.x * 256 + tid;
    int v = (i < N_NODES) ? cnt[i] : 0;
    s[tid] = v;
    __syncthreads();
#pragma unroll
    for (int off = 1; off < 256; off <<= 1) {
        int t = 0;
        if (tid >= off) t = s[tid - off];
        __syncthreads();
        if (tid >= off) s[tid] += t;
        __syncthreads();
    }
    if (i < N_NODES) scanout[i] = s[tid];
    if (tid == 255) bsum[blockIdx.x] = s[255];
}

// single block: exclusive scan of NBLK block sums, in place
__global__ void scan2_kernel(int* __restrict__ bsum) {
    __shared__ int s[512];
    int tid = threadIdx.x;
    int v = (tid < NBLK) ? bsum[tid] : 0;
    s[tid] = v;
    __syncthreads();
#pragma unroll
    for (int off = 1; off < 512; off <<= 1) {
        int t = 0;
        if (tid >= off) t = s[tid - off];
        __syncthreads();
        if (tid >= off) s[tid] += t;
        __syncthreads();
    }
    if (tid < NBLK) bsum[tid] = s[tid] - v;  // exclusive
}

// rowptr (exclusive) + cursor copy
__global__ void scan3_kernel(const int* __restrict__ cnt,
                             const int* __restrict__ scanout,
                             const int* __restrict__ bsum,
                             int* __restrict__ rowptr, int* __restrict__ cur) {
    int i = blockIdx.x * 256 + threadIdx.x;
    if (i < N_NODES) {
        int excl = scanout[i] + bsum[i >> 8] - cnt[i];
        rowptr[i] = excl;
        cur[i] = excl;
    }
    if (i == 0) rowptr[N_NODES] = N_EDGES;
}

__global__ void fill_kernel(const int* __restrict__ src, const int* __restrict__ dst,
                            int* __restrict__ cur,
                            int* __restrict__ eidx, int* __restrict__ srcs) {
    int e = blockIdx.x * blockDim.x + threadIdx.x;
    if (e < N_EDGES) {
        int pos = atomicAdd(&cur[dst[e]], 1);
        eidx[pos] = e;
        srcs[pos] = src[e];
    }
}

// ===========================================================================
// WeWl = We @ Wl (32x128), beWl = be @ Wl (128)
// ===========================================================================
__global__ void wewl_kernel(const float* __restrict__ We, const float* __restrict__ be,
                            const float* __restrict__ Wl,
                            float* __restrict__ WeWl, float* __restrict__ beWl) {
    int idx = blockIdx.x * 256 + threadIdx.x;
    if (idx >= 33 * 128) return;
    int r = idx >> 7;
    int n = idx & 127;
    float s = 0.f;
    if (r < 32) {
        for (int j = 0; j < 128; ++j) s += We[r * 128 + j] * Wl[j * 128 + n];
        WeWl[r * 128 + n] = s;
    } else {
        for (int j = 0; j < 128; ++j) s += be[j] * Wl[j * 128 + n];
        beWl[n] = s;
    }
}

// ===========================================================================
// Fused SAGE layer: CSR gather-aggregate + node GEMM + ReLU.
// out[i] = relu( (sum_x@Wl + sum_ea@WeWl)/max(d,1) + 1{d>0}*beWl + bl + x[i]@Wr + br )
// block = 256 threads, 8 nodes/block. N_NODES = 8*12500 exactly.
// ===========================================================================
__global__ __launch_bounds__(256) void sage_layer_kernel(
        const float* __restrict__ xin,
        const int* __restrict__ rowptr,
        const int* __restrict__ eidx,
        const int* __restrict__ srcs,
        const float* __restrict__ ea,
        const float* __restrict__ WeWl,
        const float* __restrict__ beWl,
        const float* __restrict__ Wl,
        const float* __restrict__ bl,
        const float* __restrict__ Wr,
        const float* __restrict__ br,
        float* __restrict__ out) {
    __shared__ float s_mean[8][HIDDEN];
    __shared__ float s_x[8][HIDDEN];
    __shared__ float s_eam[8][EDGE_DIM];
    __shared__ int s_start[8];
    __shared__ int s_cnt[8];

    int t = threadIdx.x;
    int n0 = blockIdx.x * 8;

    if (t < 8) {
        int a = rowptr[n0 + t];
        s_start[t] = a;
        s_cnt[t] = rowptr[n0 + t + 1] - a;
    }
    __syncthreads();

    int f = t & 127;
    int g = t >> 7;  // half-block 0/1

    // ---- x gather: half g handles nodes g*4 .. g*4+3 (128 threads = feature f)
#pragma unroll
    for (int j = 0; j < 4; ++j) {
        int ln = g * 4 + j;
        int n = n0 + ln;
        s_x[ln][f] = xin[n * HIDDEN + f];
        int st = s_start[ln], c = s_cnt[ln];
        float acc = 0.f;
        for (int q = 0; q < c; ++q) {
            int sn = srcs[st + q];
            acc += xin[sn * HIDDEN + f];
        }
        s_mean[ln][f] = acc / (float)(c > 0 ? c : 1);
    }

    // ---- ea gather: 8 nodes x 32 dims
    {
        int ln = t >> 5;
        int k = t & 31;
        int st = s_start[ln], c = s_cnt[ln];
        float acc = 0.f;
        for (int q = 0; q < c; ++q) {
            int e = eidx[st + q];
            acc += ea[e * EDGE_DIM + k];
        }
        s_eam[ln][k] = acc / (float)(c > 0 ? c : 1);
    }
    __syncthreads();

    // ---- GEMM: K = 128 (Wl) + 128 (Wr) + 32 (WeWl)
    int nb = g * 4;
    float bias = bl[f] + br[f];
    float bw = beWl[f];
    float acc0 = bias + (s_cnt[nb + 0] > 0 ? bw : 0.f);
    float acc1 = bias + (s_cnt[nb + 1] > 0 ? bw : 0.f);
    float acc2 = bias + (s_cnt[nb + 2] > 0 ? bw : 0.f);
    float acc3 = bias + (s_cnt[nb + 3] > 0 ? bw : 0.f);

#pragma unroll 2
    for (int k = 0; k < HIDDEN; k += 4) {
        float4 m0 = *(const float4*)&s_mean[nb + 0][k];
        float4 m1 = *(const float4*)&s_mean[nb + 1][k];
        float4 m2 = *(const float4*)&s_mean[nb + 2][k];
        float4 m3 = *(const float4*)&s_mean[nb + 3][k];
        float4 x0 = *(const float4*)&s_x[nb + 0][k];
        float4 x1 = *(const float4*)&s_x[nb + 1][k];
        float4 x2 = *(const float4*)&s_x[nb + 2][k];
        float4 x3 = *(const float4*)&s_x[nb + 3][k];
        const float* m0p = (const float*)&m0;
        const float* m1p = (const float*)&m1;
        const float* m2p = (const float*)&m2;
        const float* m3p = (const float*)&m3;
        const float* x0p = (const float*)&x0;
        const float* x1p = (const float*)&x1;
        const float* x2p = (const float*)&x2;
        const float* x3p = (const float*)&x3;
#pragma unroll
        for (int u = 0; u < 4; ++u) {
            float wl = Wl[(k + u) * HIDDEN + f];
            float wr = Wr[(k + u) * HIDDEN + f];
            acc0 += m0p[u] * wl + x0p[u] * wr;
            acc1 += m1p[u] * wl + x1p[u] * wr;
            acc2 += m2p[u] * wl + x2p[u] * wr;
            acc3 += m3p[u] * wl + x3p[u] * wr;
        }
    }
#pragma unroll 4
    for (int k = 0; k < EDGE_DIM; ++k) {
        float ww = WeWl[k * HIDDEN + f];
        acc0 += s_eam[nb + 0][k] * ww;
        acc1 += s_eam[nb + 1][k] * ww;
        acc2 += s_eam[nb + 2][k] * ww;
        acc3 += s_eam[nb + 3][k] * ww;
    }

    float accs[4] = {acc0, acc1, acc2, acc3};
#pragma unroll
    for (int j = 0; j < 4; ++j) {
        float v = accs[j];
        out[(n0 + nb + j) * HIDDEN + f] = v > 0.f ? v : 0.f;
    }
}

// ===========================================================================
// Wp1 bf16 fragment swizzle (unchanged from R2)
// ===========================================================================
__global__ void wp1_swizzle_kernel(const float* __restrict__ Wp1,
                                   unsigned short* __restrict__ Wp1s) {
    int idx = blockIdx.x * blockDim.x + threadIdx.x;  // 32768 total
    int j = idx & 7;
    int lane = (idx >> 3) & 63;
    int ks = (idx >> 9) & 7;
    int nt = (idx >> 12) & 7;
    int k = ks * 32 + ((lane >> 4) & 3) * 8 + j;
    int n = nt * 16 + (lane & 15);
    Wp1s[idx] = f2bf(Wp1[k * HIDDEN + n]);
}

// ===========================================================================
// Edge MLP via MFMA (unchanged from R2)
// ===========================================================================
#define HE_PITCH 264
__global__ __launch_bounds__(256) void edge_mlp_mfma_kernel(
        const float* __restrict__ h,
        const int* __restrict__ src,
        const int* __restrict__ dst,
        const unsigned short* __restrict__ Wp1s,
        const float* __restrict__ bp1,
        const float* __restrict__ Wp2,
        const float* __restrict__ bp2,
        float* __restrict__ out) {
    __shared__ unsigned short s_he[64 * HE_PITCH];

    int t = threadIdx.x;
    int e0 = blockIdx.x * 64;

    int lane32 = t & 31;
    int hr0 = t >> 5;
    for (int hr = hr0; hr < 128; hr += 8) {
        int e = e0 + (hr >> 1);
        int node = (hr & 1) ? dst[e] : src[e];
        float4 v = *(const float4*)&h[node * HIDDEN + lane32 * 4];
        ushort4 w;
        w.x = f2bf(v.x); w.y = f2bf(v.y); w.z = f2bf(v.z); w.w = f2bf(v.w);
        *(ushort4*)&s_he[(hr >> 1) * HE_PITCH + (hr & 1) * 128 + lane32 * 4] = w;
    }
    __syncthreads();

    int wave = t >> 6;
    int lane = t & 63;
    int col = lane & 15;
    int kgrp = lane >> 4;

    f32x4 acc[8];
#pragma unroll
    for (int nt = 0; nt < 8; ++nt) acc[nt] = (f32x4){0.f, 0.f, 0.f, 0.f};

    const bf16x8* __restrict__ Wb = (const bf16x8*)Wp1s;
    const unsigned abase = (wave * 16 + col) * HE_PITCH + kgrp * 8;

#pragma unroll
    for (int ks = 0; ks < 8; ++ks) {
        bf16x8 afrag = *(const bf16x8*)&s_he[abase + ks * 32];
#pragma unroll
        for (int nt = 0; nt < 8; ++nt) {
            bf16x8 bfrag = Wb[(nt * 8 + ks) * 64 + lane];
            acc[nt] = __builtin_amdgcn_mfma_f32_16x16x32_bf16(afrag, bfrag, acc[nt], 0, 0, 0);
        }
    }

    float z[8][4];
#pragma unroll
    for (int nt = 0; nt < 8; ++nt) {
        float b = bp1[nt * 16 + col];
#pragma unroll
        for (int r = 0; r < 4; ++r) {
            float v = acc[nt][r] + b;
            z[nt][r] = v > 0.f ? v : 0.f;
        }
    }

    float w2c0[8], w2c1[8];
#pragma unroll
    for (int nt = 0; nt < 8; ++nt) {
        int n = nt * 16 + col;
        w2c0[nt] = Wp2[n * 2 + 0];
        w2c1[nt] = Wp2[n * 2 + 1];
    }
    float p0[4], p1[4];
#pragma unroll
    for (int r = 0; r < 4; ++r) {
        float a0 = 0.f, a1 = 0.f;
#pragma unroll
        for (int nt = 0; nt < 8; ++nt) {
            a0 += z[nt][r] * w2c0[nt];
            a1 += z[nt][r] * w2c1[nt];
        }
        p0[r] = a0; p1[r] = a1;
    }
#pragma unroll
    for (int m = 8; m >= 1; m >>= 1) {
#pragma unroll
        for (int r = 0; r < 4; ++r) {
            p0[r] += __shfl_xor(p0[r], m);
            p1[r] += __shfl_xor(p1[r], m);
        }
    }
    if (col < 2) {
        float bias = bp2[col];
#pragma unroll
        for (int r = 0; r < 4; ++r) {
            int e = e0 + wave * 16 + kgrp * 4 + r;
            out[e * 2 + col] = (col == 0 ? p0[r] : p1[r]) + bias;
        }
    }
}

// ===========================================================================
extern "C" void kernel_launch(void* const* d_in, const int* in_sizes, int n_in,
                              void* d_out, int out_size, void* d_ws, size_t ws_size,
                              hipStream_t stream) {
    const float* x   = (const float*)d_in[0];
    const int*   ei  = (const int*)d_in[1];
    const float* ea  = (const float*)d_in[2];
    const float* We1 = (const float*)d_in[3];
    const float* be1 = (const float*)d_in[4];
    const float* Wl1 = (const float*)d_in[5];
    const float* bl1 = (const float*)d_in[6];
    const float* Wr1 = (const float*)d_in[7];
    const float* br1 = (const float*)d_in[8];
    const float* We2 = (const float*)d_in[9];
    const float* be2 = (const float*)d_in[10];
    const float* Wl2 = (const float*)d_in[11];
    const float* bl2 = (const float*)d_in[12];
    const float* Wr2 = (const float*)d_in[13];
    const float* br2 = (const float*)d_in[14];
    const float* Wp1 = (const float*)d_in[15];
    const float* bp1 = (const float*)d_in[16];
    const float* Wp2 = (const float*)d_in[17];
    const float* bp2 = (const float*)d_in[18];
    float* out = (float*)d_out;

    const int* src = ei;
    const int* dst = ei + N_EDGES;

    char* ws = (char*)d_ws;
    // byte offsets (all 512-aligned)
    int*   cnt     = (int*)(ws + 0);         // 400 KB slot
    int*   scanout = (int*)(ws + 409600);
    int*   bsum    = (int*)(ws + 819200);    // 8 KB slot
    int*   rowptr  = (int*)(ws + 827392);
    int*   cur     = (int*)(ws + 1236992);
    int*   eidx    = (int*)(ws + 1646592);   // 2.4 MB
    int*   srcs    = (int*)(ws + 4046592);   // 2.4 MB
    float* WeWl1   = (float*)(ws + 6446592);
    float* beWl1   = (float*)(ws + 6462976);
    float* WeWl2   = (float*)(ws + 6463488);
    float* beWl2   = (float*)(ws + 6479872);
    float* h1      = (float*)(ws + 8388608);              // 51.2 MB
    float* h2      = (float*)(ws + 8388608 + 51200000);   // 51.2 MB
    unsigned short* Wp1s = (unsigned short*)(ws + 8388608 + 2 * 51200000);

    const int EB = (N_EDGES + 255) / 256;

    // ---- CSR build ----
    hipMemsetAsync(cnt, 0, N_NODES * sizeof(int), stream);
    hist_kernel<<<EB, 256, 0, stream>>>(dst, cnt);
    scan1_kernel<<<NBLK, 256, 0, stream>>>(cnt, scanout, bsum);
    scan2_kernel<<<1, 512, 0, stream>>>(bsum);
    scan3_kernel<<<NBLK, 256, 0, stream>>>(cnt, scanout, bsum, rowptr, cur);
    fill_kernel<<<EB, 256, 0, stream>>>(src, dst, cur, eidx, srcs);

    // ---- folded weights ----
    wewl_kernel<<<17, 256, 0, stream>>>(We1, be1, Wl1, WeWl1, beWl1);
    wewl_kernel<<<17, 256, 0, stream>>>(We2, be2, Wl2, WeWl2, beWl2);

    // ---- layer 1 / layer 2 ----
    sage_layer_kernel<<<N_NODES / 8, 256, 0, stream>>>(
        x, rowptr, eidx, srcs, ea, WeWl1, beWl1, Wl1, bl1, Wr1, br1, h1);
    sage_layer_kernel<<<N_NODES / 8, 256, 0, stream>>>(
        h1, rowptr, eidx, srcs, ea, WeWl2, beWl2, Wl2, bl2, Wr2, br2, h2);

    // ---- edge predictor (MFMA) ----
    wp1_swizzle_kernel<<<32768 / 256, 256, 0, stream>>>(Wp1, Wp1s);
    edge_mlp_mfma_kernel<<<N_EDGES / 64, 256, 0, stream>>>(
        h2, src, dst, Wp1s, bp1, Wp2, bp2, out);
}